// Round 9
// baseline (558.410 us; speedup 1.0000x reference)
//
#include <hip/hip_runtime.h>
#include <hip/hip_bf16.h>

// Problem constants
#define BATCH 128
#define TSTEPS 64
#define EMB 256
#define HID 512
#define GATES 2048   // 4*HID
#define NFEAT 2048
#define GPB 4        // batch-groups per block (systolic phases per step)

typedef __bf16 bf16_t;
typedef __attribute__((ext_vector_type(8))) __bf16 bf16x8;
typedef __attribute__((ext_vector_type(4))) float f32x4;

#define MFMA16 __builtin_amdgcn_mfma_f32_16x16x32_bf16

// A/B fragment from row-major global: lane l -> row = row0 + (l&15), k = k0 + (l>>4)*8.
__device__ __forceinline__ bf16x8 frag16(const bf16_t* __restrict__ base, int row0, int stride,
                                         int k0, int lane) {
    return *(const bf16x8*)(base + (size_t)(row0 + (lane & 15)) * stride + k0 + ((lane >> 4) << 3));
}

__device__ __forceinline__ float sigm(float x) { return 1.f / (1.f + __expf(-x)); }
__device__ __forceinline__ float tanh_f(float x) { return 1.f - 2.f / (__expf(2.f * x) + 1.f); }

__device__ __forceinline__ float bflo(unsigned w) {
    return __builtin_bit_cast(float, (w & 0xffffu) << 16);
}
__device__ __forceinline__ float bfhi(unsigned w) {
    return __builtin_bit_cast(float, w & 0xffff0000u);
}
__device__ __forceinline__ unsigned f2bf(float x) {
    return (unsigned)__builtin_bit_cast(unsigned short, (bf16_t)x);
}

// 8B packet store {data, tag}, LLC-coherent, fire-and-forget (no drain ever).
__device__ __forceinline__ void st_sys_v2(void* p, unsigned lo, unsigned hi) {
    uint2 v = make_uint2(lo, hi);
    asm volatile("global_store_dwordx2 %0, %1, off sc0 sc1" :: "v"(p), "v"(v) : "memory");
}

// In-flight slot: 4x16B packet data (2 chunks of the group h-image) + 4 xproj dwords.
struct Slot { uint4 a, b, c, d; unsigned x0, x1, x2, x3; };

// Issue 8 loads for a slot, NO wait (counted later via vmcnt(N)).
__device__ __forceinline__ void issue_slot(Slot& S, const void* q0, const void* q2,
                                           const void* xr) {
    asm volatile(
        "global_load_dwordx4 %0, %8, off sc0 sc1\n\t"
        "global_load_dwordx4 %1, %8, off offset:16 sc0 sc1\n\t"
        "global_load_dwordx4 %2, %9, off sc0 sc1\n\t"
        "global_load_dwordx4 %3, %9, off offset:16 sc0 sc1\n\t"
        "global_load_dword %4, %10, off\n\t"
        "global_load_dword %5, %10, off offset:1024\n\t"
        "global_load_dword %6, %10, off offset:2048\n\t"
        "global_load_dword %7, %10, off offset:3072"
        : "=&v"(S.a), "=&v"(S.b), "=&v"(S.c), "=&v"(S.d),
          "=&v"(S.x0), "=&v"(S.x1), "=&v"(S.x2), "=&v"(S.x3)
        : "v"(q0), "v"(q2), "v"(xr)
        : "memory");
}

// Blocking re-poll of the 4 packet chunks (rare path; xproj regs untouched).
__device__ __forceinline__ void reload_pkts(Slot& S, const void* q0, const void* q2) {
    asm volatile(
        "global_load_dwordx4 %0, %4, off sc0 sc1\n\t"
        "global_load_dwordx4 %1, %4, off offset:16 sc0 sc1\n\t"
        "global_load_dwordx4 %2, %5, off sc0 sc1\n\t"
        "global_load_dwordx4 %3, %5, off offset:16 sc0 sc1\n\t"
        "s_waitcnt vmcnt(0)"
        : "=&v"(S.a), "=&v"(S.b), "=&v"(S.c), "=&v"(S.d)
        : "v"(q0), "v"(q2)
        : "memory");
}

// LDS-only barrier: lgkmcnt(0) + s_barrier. NO vmcnt drain -> prefetches/stores stay in flight.
__device__ __forceinline__ void bar_lds() {
    __builtin_amdgcn_sched_barrier(0);
    asm volatile("s_waitcnt lgkmcnt(0)" ::: "memory");
    __builtin_amdgcn_s_barrier();
    __builtin_amdgcn_sched_barrier(0);
}

// ---------------- prep: weights->bf16, bias sum, zero parity-0 packets (h_0, tag 0) ----------
__global__ __launch_bounds__(256) void k_prep(
    const float* __restrict__ Wih, const float* __restrict__ Whh, const float* __restrict__ Wout,
    const float* __restrict__ bih, const float* __restrict__ bhh,
    bf16_t* __restrict__ wih_b, bf16_t* __restrict__ whh_b, bf16_t* __restrict__ wout_b,
    float* __restrict__ biassum, unsigned long long* __restrict__ pkt0) {
    const int N1 = GATES * EMB;
    const int N2 = GATES * HID;
    const int N3 = NFEAT * HID;
    const int N4 = GATES;
    const int N5 = 32768;                // parity-0 packets {h=0, tag=0}
    const long total = (long)N1 + N2 + N3 + N4 + N5;
    for (long i = (long)blockIdx.x * blockDim.x + threadIdx.x; i < total;
         i += (long)gridDim.x * blockDim.x) {
        long x = i;
        if (x < N1) { wih_b[x] = (bf16_t)Wih[x]; continue; } x -= N1;
        if (x < N2) { whh_b[x] = (bf16_t)Whh[x]; continue; } x -= N2;
        if (x < N3) { wout_b[x] = (bf16_t)Wout[x]; continue; } x -= N3;
        if (x < N4) { biassum[x] = bih[x] + bhh[x]; continue; } x -= N4;
        pkt0[x] = 0ull;
    }
}

// ---------------- x_proj GEMM with inline gather: one t per block-row ----------------
__global__ __launch_bounds__(256) void k_xproj(
    const int* __restrict__ m, const float* __restrict__ emb_tab,
    const bf16_t* __restrict__ Wih, const float* __restrict__ biassum,
    bf16_t* __restrict__ xproj) {     // [8192][2048] bf16, row = t*128+b
    int lane = threadIdx.x & 63, w = threadIdx.x >> 6;
    int t = blockIdx.x;                  // 0..63
    int b0 = (w >> 1) * 64;              // batch base for this wave
    int g0 = blockIdx.y * 128 + (w & 1) * 64;
    int q = lane >> 4;
    int tok[4];
    #pragma unroll
    for (int i = 0; i < 4; i++)
        tok[i] = m[(b0 + 16 * i + (lane & 15)) * TSTEPS + t];
    f32x4 acc[4][4] = {};
    #pragma unroll
    for (int k = 0; k < EMB; k += 32) {
        bf16x8 af[4], bf[4];
        #pragma unroll
        for (int i = 0; i < 4; i++) {
            const float* src = emb_tab + (size_t)tok[i] * EMB + k + q * 8;
            float4 lo = *(const float4*)(src);
            float4 hi = *(const float4*)(src + 4);
            bf16x8 v;
            v[0] = (bf16_t)lo.x; v[1] = (bf16_t)lo.y; v[2] = (bf16_t)lo.z; v[3] = (bf16_t)lo.w;
            v[4] = (bf16_t)hi.x; v[5] = (bf16_t)hi.y; v[6] = (bf16_t)hi.z; v[7] = (bf16_t)hi.w;
            af[i] = v;
        }
        #pragma unroll
        for (int j = 0; j < 4; j++) bf[j] = frag16(Wih, g0 + 16 * j, EMB, k, lane);
        #pragma unroll
        for (int i = 0; i < 4; i++)
            #pragma unroll
            for (int j = 0; j < 4; j++)
                acc[i][j] = MFMA16(af[i], bf[j], acc[i][j], 0, 0, 0);
    }
    #pragma unroll
    for (int j = 0; j < 4; j++) {
        int g = g0 + 16 * j + (lane & 15);
        float bs = biassum[g];
        #pragma unroll
        for (int i = 0; i < 4; i++)
            #pragma unroll
            for (int r = 0; r < 4; r++) {
                int row = t * BATCH + b0 + 16 * i + (q << 2) + r;
                xproj[(size_t)row * GATES + g] = (bf16_t)(acc[i][j][r] + bs);
            }
    }
}

// ---------------- recurrence: 16 blocks = 8 strips x 2 sets, 4 groups/block systolic --------
// Block (set,s): strip s (j-cols [s*64,s*64+64) per gate), groups set*4..set*4+3 cycled as 4
// phases/step. Tagged 8B packets (R7 protocol) exchanged at LLC; prefetch issued 2 phases
// ahead; steady-state wait = vmcnt(10) (per-phase VMEM = 8 loads + 1 store; newest-10 at the
// wait = store(k-2)+loads(k+1)x8+store(k-1), so slot-k loads are forced complete). Barriers are
// LDS-only (lgkmcnt+s_barrier): the pipeline never drains. Ordering of slot-register reads
// after the counted vmcnt is enforced by sched_barrier(0) (rule #18 fence).
__global__ __launch_bounds__(512, 1) void k_rnn(
    const bf16_t* __restrict__ xp,    // [8192][2048] bf16
    const bf16_t* __restrict__ whh,   // [2048][512] bf16
    char* __restrict__ hbuf,          // packets: 2 parity x 256KB
    bf16_t* __restrict__ hfin) {      // dense frag image of h_64
    __shared__ __align__(16) char hstage[16384];   // [16 kt][64 lane][16B]
    __shared__ float gex[4][16][66];               // gate exchange
    const int tid = threadIdx.x;
    const int lane = tid & 63, w = tid >> 6;
    const int s   = blockIdx.x & 7;         // strip (spread over XCDs)
    const int set = blockIdx.x >> 3;        // 0..1 (independent pipelines)
    const int g = w >> 1, hh = w & 1;

    // --- preload Whh slice into registers and pin ---
    bf16x8 Bf0[16], Bf1[16];
    {
        const bf16_t* wb = whh + (size_t)(g * HID + s * 64 + hh * 32) * HID;
        #pragma unroll
        for (int kt = 0; kt < 16; ++kt) {
            Bf0[kt] = frag16(wb, 0, HID, kt * 32, lane);
            Bf1[kt] = frag16(wb, 16, HID, kt * 32, lane);
        }
        #pragma unroll
        for (int kt = 0; kt < 16; ++kt)
            asm volatile("" : "+v"(Bf0[kt]), "+v"(Bf1[kt]));
    }

    const int r_up = tid >> 5;              // 0..15 (batch row within group)
    const int c0 = (tid & 31) * 2;          // 0..62 (local col pair)
    float cst[GPB][2] = {};                 // cell state per group (static-indexed)

    int pk8;  // byte offset of this thread's packet pair within a (parity,group) region
    {
        int j = s * 64 + c0;
        int kt = j >> 5;
        int lane_p = (((j & 31) >> 3) << 4) | r_up;
        pk8 = (kt * 256 + lane_p * 4 + ((j & 7) >> 1)) * 8;
    }

    Slot slot0, slot1;

#define PKQ0(T_, PH) ((const void*)(hbuf + (((T_) & 1) ? 262144 : 0) \
                      + (size_t)((set * GPB + (PH)) * 32768) + (size_t)tid * 32))
#define PKQ2(T_, PH) ((const void*)(hbuf + (((T_) & 1) ? 262144 : 0) \
                      + (size_t)((set * GPB + (PH)) * 32768) + (size_t)(tid + 512) * 32))
#define XRP(T_, PH)  ((const void*)(xp + ((size_t)((T_) * BATCH + (set * GPB + (PH)) * 16 + r_up)) * GATES \
                      + s * 64 + c0))

    // prologue: prime phases 0 and 1 of step 0
    issue_slot(slot0, PKQ0(0, 0), PKQ2(0, 0), XRP(0, 0));
    issue_slot(slot1, PKQ0(0, 1), PKQ2(0, 1), XRP(0, 1));

#define PHASE(IDX, VM, T_) do {                                                            \
    Slot& S = ((IDX) & 1) ? slot1 : slot0;                                                 \
    asm volatile("s_waitcnt vmcnt(%0)" :: "i"(VM) : "memory");                             \
    __builtin_amdgcn_sched_barrier(0);                                                     \
    { unsigned tg = (unsigned)(T_);                                                        \
      while (!(S.a.y == tg && S.a.w == tg && S.b.y == tg && S.b.w == tg &&                 \
               S.c.y == tg && S.c.w == tg && S.d.y == tg && S.d.w == tg))                  \
          reload_pkts(S, PKQ0(T_, IDX), PKQ2(T_, IDX)); }                                  \
    unsigned xv0 = S.x0, xv1 = S.x1, xv2 = S.x2, xv3 = S.x3;                               \
    *(uint4*)(hstage + (size_t)tid * 16) = make_uint4(S.a.x, S.a.z, S.b.x, S.b.z);         \
    *(uint4*)(hstage + (size_t)(tid + 512) * 16) = make_uint4(S.c.x, S.c.z, S.d.x, S.d.z); \
    { const int pt = ((IDX) + 2) & 3;                                                      \
      const int tt = ((IDX) < 2) ? (T_) : ((T_) + 1);                                      \
      issue_slot(S, PKQ0(tt, pt), PKQ2(tt, pt), XRP(tt, pt)); }                            \
    bar_lds(); /* B1: hstage ready */                                                      \
    f32x4 a0 = {}, a1 = {};                                                                \
    { const bf16_t* hs = (const bf16_t*)hstage;                                            \
      _Pragma("unroll")                                                                    \
      for (int kt = 0; kt < 16; ++kt) {                                                    \
          bf16x8 av = *(const bf16x8*)(hs + kt * 512 + lane * 8);                          \
          a0 = MFMA16(av, Bf0[kt], a0, 0, 0, 0);                                           \
          a1 = MFMA16(av, Bf1[kt], a1, 0, 0, 0);                                           \
      } }                                                                                  \
    { const int jj = lane & 15, qq = lane >> 4;                                            \
      _Pragma("unroll")                                                                    \
      for (int rr = 0; rr < 4; ++rr) {                                                     \
          gex[g][qq * 4 + rr][hh * 32 + jj]      = a0[rr];                                 \
          gex[g][qq * 4 + rr][hh * 32 + 16 + jj] = a1[rr];                                 \
      } }                                                                                  \
    bar_lds(); /* B2: gex ready; hstage reusable */                                        \
    { float2 gi = *(const float2*)&gex[0][r_up][c0];                                       \
      float2 gf = *(const float2*)&gex[1][r_up][c0];                                       \
      float2 gg2 = *(const float2*)&gex[2][r_up][c0];                                      \
      float2 go = *(const float2*)&gex[3][r_up][c0];                                       \
      float iv0 = gi.x + bflo(xv0), iv1 = gi.y + bfhi(xv0);                                \
      float fv0 = gf.x + bflo(xv1), fv1 = gf.y + bfhi(xv1);                                \
      float gv0 = gg2.x + bflo(xv2), gv1 = gg2.y + bfhi(xv2);                              \
      float ov0 = go.x + bflo(xv3), ov1 = go.y + bfhi(xv3);                                \
      cst[IDX][0] = sigm(fv0) * cst[IDX][0] + sigm(iv0) * tanh_f(gv0);                     \
      cst[IDX][1] = sigm(fv1) * cst[IDX][1] + sigm(iv1) * tanh_f(gv1);                     \
      float h0v = sigm(ov0) * tanh_f(cst[IDX][0]);                                         \
      float h1v = sigm(ov1) * tanh_f(cst[IDX][1]);                                         \
      unsigned pack = f2bf(h0v) | (f2bf(h1v) << 16);                                       \
      char* pst = hbuf + ((((T_) + 1) & 1) ? 262144 : 0)                                   \
                + (size_t)((set * GPB + (IDX)) * 32768) + pk8;                             \
      st_sys_v2(pst, pack, (unsigned)((T_) + 1));                                          \
      if ((T_) == TSTEPS - 1)                                                              \
          *((unsigned*)hfin + ((size_t)(set * GPB + (IDX)) << 12) + (pk8 >> 3)) = pack;    \
    }                                                                                      \
} while (0)

    // t = 0: prologue-specific wait counts (16 outstanding; slot0 newest-8 -> vmcnt(8), etc.)
    PHASE(0, 8, 0);
    PHASE(1, 9, 0);
    PHASE(2, 10, 0);
    PHASE(3, 10, 0);
    for (int t = 1; t < TSTEPS; ++t) {
        PHASE(0, 10, t);
        PHASE(1, 10, t);
        PHASE(2, 10, t);
        PHASE(3, 10, t);
    }
#undef PHASE
#undef PKQ0
#undef PKQ2
#undef XRP
}

// A-frag from dense fragment image [group][16 kt][64 lane][8]
__device__ __forceinline__ bf16x8 frag_piece(const bf16_t* hb, int group, int kt, int lane) {
    return *(const bf16x8*)(hb + (size_t)group * 8192 + kt * 512 + lane * 8);
}

// ---------------- output GEMM: h[128,512] x Wout^T + b_out -> out f32 [128][2048] ------------
__global__ __launch_bounds__(256) void k_out(
    const bf16_t* __restrict__ h,      // hfin dense frag image
    const bf16_t* __restrict__ Wout,
    const float* __restrict__ bout,
    float* __restrict__ out) {
    int lane = threadIdx.x & 63, w = threadIdx.x >> 6;
    int r0 = blockIdx.x * 32 + (w & 1) * 16;
    int g0 = blockIdx.y * 128 + (w >> 1) * 64;
    int group = r0 >> 4;
    f32x4 acc[4] = {};
    #pragma unroll 4
    for (int kt = 0; kt < 16; ++kt) {
        bf16x8 a = frag_piece(h, group, kt, lane);
        #pragma unroll
        for (int t = 0; t < 4; t++) {
            bf16x8 b = frag16(Wout, g0 + 16 * t, HID, kt * 32, lane);
            acc[t] = MFMA16(a, b, acc[t], 0, 0, 0);
        }
    }
    #pragma unroll
    for (int t = 0; t < 4; t++) {
        int g = g0 + 16 * t + (lane & 15);
        float bs = bout[g];
        #pragma unroll
        for (int r = 0; r < 4; r++) {
            int row = r0 + ((lane >> 4) << 2) + r;
            out[(size_t)row * NFEAT + g] = acc[t][r] + bs;
        }
    }
}

extern "C" void kernel_launch(void* const* d_in, const int* in_sizes, int n_in,
                              void* d_out, int out_size, void* d_ws, size_t ws_size,
                              hipStream_t stream) {
    const int*   m       = (const int*)d_in[0];
    // d_in[1] = images (unused by reference)
    const float* emb_tab = (const float*)d_in[2];
    const float* W_ih    = (const float*)d_in[3];
    const float* W_hh    = (const float*)d_in[4];
    const float* b_ih    = (const float*)d_in[5];
    const float* b_hh    = (const float*)d_in[6];
    const float* W_out   = (const float*)d_in[7];
    const float* b_out   = (const float*)d_in[8];

    char* ws = (char*)d_ws;
    bf16_t* xpb     = (bf16_t*)(ws + 0);          // 8192*2048*2 = 33554432
    bf16_t* wih_b   = (bf16_t*)(ws + 33554432);   // 1048576
    bf16_t* whh_b   = (bf16_t*)(ws + 34603008);   // 2097152
    bf16_t* wout_b  = (bf16_t*)(ws + 36700160);   // 2097152
    char*   hbuf    = (char*)  (ws + 38797312);   // packets 2*262144 = 524288
    bf16_t* hfin    = (bf16_t*)(ws + 39321600);   // 131072
    float*  biassum = (float*) (ws + 39452672);   // 8192

    k_prep<<<dim3(1024), dim3(256), 0, stream>>>(W_ih, W_hh, W_out, b_ih, b_hh,
                                                 wih_b, whh_b, wout_b, biassum,
                                                 (unsigned long long*)hbuf);

    k_xproj<<<dim3(64, 16), dim3(256), 0, stream>>>(m, emb_tab, wih_b, biassum, xpb);

    k_rnn<<<dim3(16), dim3(512), 0, stream>>>(xpb, whh_b, hbuf, hfin);

    k_out<<<dim3(4, 16), dim3(256), 0, stream>>>(hfin, wout_b, b_out, (float*)d_out);
}

// Round 10
// 331.999 us; speedup vs baseline: 1.6820x; 1.6820x over previous
//
#include <hip/hip_runtime.h>
#include <hip/hip_bf16.h>

// Problem constants
#define BATCH 128
#define TSTEPS 64
#define EMB 256
#define HID 512
#define GATES 2048   // 4*HID
#define NFEAT 2048

typedef __bf16 bf16_t;
typedef __attribute__((ext_vector_type(8))) __bf16 bf16x8;
typedef __attribute__((ext_vector_type(4))) float f32x4;

#define MFMA16 __builtin_amdgcn_mfma_f32_16x16x32_bf16

// A/B fragment from row-major bf16: lane l -> row = row0 + (l&15), k = k0 + (l>>4)*8.
__device__ __forceinline__ bf16x8 frag16(const bf16_t* __restrict__ base, int row0, int stride,
                                         int k0, int lane) {
    return *(const bf16x8*)(base + (size_t)(row0 + (lane & 15)) * stride + k0 + ((lane >> 4) << 3));
}
// Same fragment but from f32 source with inline convert (weights stay f32 in HBM).
__device__ __forceinline__ bf16x8 frag16f(const float* __restrict__ base, int row0, int stride,
                                          int k0, int lane) {
    const float* p = base + (size_t)(row0 + (lane & 15)) * stride + k0 + ((lane >> 4) << 3);
    float4 lo = *(const float4*)p;
    float4 hi = *(const float4*)(p + 4);
    bf16x8 v;
    v[0] = (bf16_t)lo.x; v[1] = (bf16_t)lo.y; v[2] = (bf16_t)lo.z; v[3] = (bf16_t)lo.w;
    v[4] = (bf16_t)hi.x; v[5] = (bf16_t)hi.y; v[6] = (bf16_t)hi.z; v[7] = (bf16_t)hi.w;
    return v;
}

__device__ __forceinline__ float sigm(float x) { return 1.f / (1.f + __expf(-x)); }
__device__ __forceinline__ float tanh_f(float x) { return 1.f - 2.f / (__expf(2.f * x) + 1.f); }

__device__ __forceinline__ float bfbits2f(unsigned b16) {
    return __builtin_bit_cast(float, b16 << 16);
}
__device__ __forceinline__ unsigned f2bf(float x) {
    return (unsigned)__builtin_bit_cast(unsigned short, (bf16_t)x);
}

// LLC-coherent (sc0sc1) primitives — bypass L1/L2, never invalidate caches.
__device__ __forceinline__ unsigned ld_sys(const unsigned* p) {
    return __hip_atomic_load(p, __ATOMIC_RELAXED, __HIP_MEMORY_SCOPE_SYSTEM);
}
__device__ __forceinline__ void st_sys(unsigned* p, unsigned v) {
    __hip_atomic_store(p, v, __ATOMIC_RELAXED, __HIP_MEMORY_SCOPE_SYSTEM);
}
__device__ __forceinline__ void st_sys_v2(void* p, unsigned lo, unsigned hi) {
    uint2 v = make_uint2(lo, hi);
    asm volatile("global_store_dwordx2 %0, %1, off sc0 sc1" :: "v"(p), "v"(v) : "memory");
}
// 4x 16B LLC loads in flight, one wait.
__device__ __forceinline__ void ld4_sys_v4(const void* p0, const void* p1,
                                           const void* p2, const void* p3,
                                           uint4& a, uint4& b, uint4& c, uint4& d) {
    asm volatile("global_load_dwordx4 %0, %4, off sc0 sc1\n\t"
                 "global_load_dwordx4 %1, %5, off sc0 sc1\n\t"
                 "global_load_dwordx4 %2, %6, off sc0 sc1\n\t"
                 "global_load_dwordx4 %3, %7, off sc0 sc1\n\t"
                 "s_waitcnt vmcnt(0)"
                 : "=&v"(a), "=&v"(b), "=&v"(c), "=&v"(d)
                 : "v"(p0), "v"(p1), "v"(p2), "v"(p3)
                 : "memory");
}

// ---------------- x_proj GEMM: inline gather + inline Wih cvt + inline bias ----------------
// Block (bx=t, by): rows t*128..+128, cols by*128..+128. 4 waves (2x2), 64x64/wave.
// Block (0,0) also zeroes the k_rnn flag region (sc0sc1 so k_rnn's LLC polls see it).
__global__ __launch_bounds__(256) void k_xproj(
    const int* __restrict__ m, const float* __restrict__ emb_tab,
    const float* __restrict__ Wih, const float* __restrict__ bih, const float* __restrict__ bhh,
    bf16_t* __restrict__ xproj, unsigned* __restrict__ flags) {
    if (blockIdx.x == 0 && blockIdx.y == 0 && threadIdx.x < 256)
        st_sys(flags + threadIdx.x, 0u);

    int lane = threadIdx.x & 63, w = threadIdx.x >> 6;
    int t = blockIdx.x;                  // 0..63
    int b0 = (w >> 1) * 64;
    int g0 = blockIdx.y * 128 + (w & 1) * 64;
    int q = lane >> 4;
    int tok[4];
    #pragma unroll
    for (int i = 0; i < 4; i++)
        tok[i] = m[(b0 + 16 * i + (lane & 15)) * TSTEPS + t];
    f32x4 acc[4][4] = {};
    #pragma unroll
    for (int k = 0; k < EMB; k += 32) {
        bf16x8 af[4], bf[4];
        #pragma unroll
        for (int i = 0; i < 4; i++) {
            const float* src = emb_tab + (size_t)tok[i] * EMB + k + q * 8;
            float4 lo = *(const float4*)(src);
            float4 hi = *(const float4*)(src + 4);
            bf16x8 v;
            v[0] = (bf16_t)lo.x; v[1] = (bf16_t)lo.y; v[2] = (bf16_t)lo.z; v[3] = (bf16_t)lo.w;
            v[4] = (bf16_t)hi.x; v[5] = (bf16_t)hi.y; v[6] = (bf16_t)hi.z; v[7] = (bf16_t)hi.w;
            af[i] = v;
        }
        #pragma unroll
        for (int j = 0; j < 4; j++) bf[j] = frag16f(Wih, g0 + 16 * j, EMB, k, lane);
        #pragma unroll
        for (int i = 0; i < 4; i++)
            #pragma unroll
            for (int j = 0; j < 4; j++)
                acc[i][j] = MFMA16(af[i], bf[j], acc[i][j], 0, 0, 0);
    }
    #pragma unroll
    for (int j = 0; j < 4; j++) {
        int g = g0 + 16 * j + (lane & 15);
        float bs = bih[g] + bhh[g];
        #pragma unroll
        for (int i = 0; i < 4; i++)
            #pragma unroll
            for (int r = 0; r < 4; r++) {
                int row = t * BATCH + b0 + 16 * i + (q << 2) + r;
                xproj[(size_t)row * GATES + g] = (bf16_t)(acc[i][j][r] + bs);
            }
    }
}

// ---------------- recurrence: 64 blocks = 8 batch-groups x 8 hidden-strips ----------------
// 256 threads = 4 waves; wave w owns col-tile ct=w (16 j-cols) for ALL 4 gates.
// TRANSPOSED GEMM: gates^T = mfma(A=Whh_frag(rows=j), B=h_frag(rows=b)) -> D row=j, col=b.
// Lane (jj=lane&15 -> b, q=lane>>4) holds acc_g[rr] for j = s*64+w*16+q*4+rr, all 4 gates
// -> cell update is LANE-LOCAL (no gate exchange, no 3rd barrier, no LDS bank conflicts).
// The 4 consecutive-j h outputs pack into one 8B half of a fragment-image chunk -> producer
// stores ONE dwordx2; consumers stage with pure 16B copies. Per-wave plain-store flags
// (no RMW); only wave 0 polls (64 pollers chip-wide). Flags zeroed by k_xproj -> monotone
// v>=t is replay-safe. Double-buffered h by step parity (skew<=1 induction as R5).
__global__ __launch_bounds__(256, 1) void k_rnn(
    const bf16_t* __restrict__ xp,    // [8192][2048] bf16, row = t*128+b
    const float* __restrict__ whh,    // [2048][512] f32 (converted inline at preload)
    char* __restrict__ hbuf,          // [2 parity][8 group][16 kt][64 lane][16B] = 2*128KB
    unsigned* __restrict__ flags) {   // [8 group][8 strip][4 wave]
    __shared__ __align__(16) char hstage[16384];   // [16 kt][64 lane][16B]
    const int tid = threadIdx.x;
    const int lane = tid & 63, w = tid >> 6;
    const int group = blockIdx.x >> 3;  // 0..7
    const int s     = blockIdx.x & 7;   // 0..7
    const int jj = lane & 15, q = lane >> 4;

    // --- preload Whh slice (f32 -> bf16) into registers and pin ---
    bf16x8 W0[16], W1[16], W2[16], W3[16];
    #pragma unroll
    for (int kt = 0; kt < 16; ++kt) {
        W0[kt] = frag16f(whh, 0 * HID + s * 64 + w * 16, HID, kt * 32, lane);
        W1[kt] = frag16f(whh, 1 * HID + s * 64 + w * 16, HID, kt * 32, lane);
        W2[kt] = frag16f(whh, 2 * HID + s * 64 + w * 16, HID, kt * 32, lane);
        W3[kt] = frag16f(whh, 3 * HID + s * 64 + w * 16, HID, kt * 32, lane);
    }
    #pragma unroll
    for (int kt = 0; kt < 16; ++kt)
        asm volatile("" : "+v"(W0[kt]), "+v"(W1[kt]), "+v"(W2[kt]), "+v"(W3[kt]));

    const int j0 = s * 64 + w * 16 + q * 4;    // this lane's first j (4 consecutive)
    // 8B packet position inside a parity image: [group][kt=j>>5][lane_f][16B], half (q&1)
    const size_t pk_off = (size_t)group * 16384 + (size_t)(j0 >> 5) * 1024
                        + (size_t)((((j0 & 31) >> 3) << 4) | jj) * 16 + (size_t)(q & 1) * 8;
    unsigned* myflag = flags + group * 32 + s * 4 + w;
    const unsigned* pollp = flags + group * 32 + (lane & 31);

    float cst[4] = {0.f, 0.f, 0.f, 0.f};

    // ---------------- t = 0: h_0 = 0 -> gates = xproj only ----------------
    {
        const bf16_t* xrow = xp + ((size_t)(group * 16 + jj)) * GATES + j0;
        uint2 xg[4];
        #pragma unroll
        for (int g = 0; g < 4; ++g) xg[g] = *(const uint2*)(xrow + g * HID);
        unsigned lo = 0, hi = 0;
        #pragma unroll
        for (int rr = 0; rr < 4; ++rr) {
            unsigned sh = (rr & 1) * 16;
            float iv = bfbits2f(((rr < 2 ? xg[0].x : xg[0].y) >> sh) & 0xffffu);
            float fv = bfbits2f(((rr < 2 ? xg[1].x : xg[1].y) >> sh) & 0xffffu);
            float gv = bfbits2f(((rr < 2 ? xg[2].x : xg[2].y) >> sh) & 0xffffu);
            float ov = bfbits2f(((rr < 2 ? xg[3].x : xg[3].y) >> sh) & 0xffffu);
            float cn = sigm(iv) * tanh_f(gv);          // c0 = 0
            cst[rr] = cn;
            unsigned hb = f2bf(sigm(ov) * tanh_f(cn));
            if (rr < 2) lo |= hb << sh; else hi |= hb << sh;
        }
        st_sys_v2(hbuf + 131072 /*parity 1*/ + pk_off, lo, hi);
        asm volatile("s_waitcnt vmcnt(0)" ::: "memory");
        if (lane == 0) st_sys(myflag, 1u);
    }

    // ---------------- t = 1..63 ----------------
    for (int t = 1; t < TSTEPS; ++t) {
        // xproj prefetch (regular cached loads; overlap the poll)
        const bf16_t* xrow = xp + ((size_t)(t * BATCH + group * 16 + jj)) * GATES + j0;
        uint2 xg[4];
        #pragma unroll
        for (int g = 0; g < 4; ++g) xg[g] = *(const uint2*)(xrow + g * HID);

        if (w == 0) {   // wave-0-only poll: all 32 wave-flags of the group >= t
            unsigned v;
            do { v = ld_sys(pollp); } while (!__all((int)(v >= (unsigned)t)));
        }
        __syncthreads();   // B1: release; also orders stage loads after poll success

        // stage h_t: pure 16B copies LLC -> LDS (image already in fragment layout)
        {
            const char* src = hbuf + (size_t)(t & 1) * 131072 + (size_t)group * 16384;
            uint4 a, b, c, d;
            ld4_sys_v4(src + (size_t)tid * 16, src + (size_t)(tid + 256) * 16,
                       src + (size_t)(tid + 512) * 16, src + (size_t)(tid + 768) * 16,
                       a, b, c, d);
            *(uint4*)(hstage + (size_t)tid * 16)         = a;
            *(uint4*)(hstage + (size_t)(tid + 256) * 16) = b;
            *(uint4*)(hstage + (size_t)(tid + 512) * 16) = c;
            *(uint4*)(hstage + (size_t)(tid + 768) * 16) = d;
        }
        __syncthreads();   // B2: hstage ready

        // transposed gates GEMM: D[j, b], K = 512; A = Whh regs, B = h from LDS
        f32x4 a0 = {}, a1 = {}, a2 = {}, a3 = {};
        #pragma unroll
        for (int kt = 0; kt < 16; ++kt) {
            bf16x8 hb = *(const bf16x8*)(hstage + kt * 1024 + lane * 16);
            a0 = MFMA16(W0[kt], hb, a0, 0, 0, 0);
            a1 = MFMA16(W1[kt], hb, a1, 0, 0, 0);
            a2 = MFMA16(W2[kt], hb, a2, 0, 0, 0);
            a3 = MFMA16(W3[kt], hb, a3, 0, 0, 0);
        }

        // lane-local cell update + single 8B packet store
        unsigned lo = 0, hi = 0;
        #pragma unroll
        for (int rr = 0; rr < 4; ++rr) {
            unsigned sh = (rr & 1) * 16;
            float iv = a0[rr] + bfbits2f(((rr < 2 ? xg[0].x : xg[0].y) >> sh) & 0xffffu);
            float fv = a1[rr] + bfbits2f(((rr < 2 ? xg[1].x : xg[1].y) >> sh) & 0xffffu);
            float gv = a2[rr] + bfbits2f(((rr < 2 ? xg[2].x : xg[2].y) >> sh) & 0xffffu);
            float ov = a3[rr] + bfbits2f(((rr < 2 ? xg[3].x : xg[3].y) >> sh) & 0xffffu);
            float cn = sigm(fv) * cst[rr] + sigm(iv) * tanh_f(gv);
            cst[rr] = cn;
            unsigned hb = f2bf(sigm(ov) * tanh_f(cn));
            if (rr < 2) lo |= hb << sh; else hi |= hb << sh;
        }
        st_sys_v2(hbuf + (size_t)((t + 1) & 1) * 131072 + pk_off, lo, hi);
        asm volatile("s_waitcnt vmcnt(0)" ::: "memory");   // wave's stores at LLC
        if (lane == 0) st_sys(myflag, (unsigned)(t + 1));
    }
    // h_64 lives in parity (63+1)&1 = 0
}

// A-frag from the fragment image [group][16 kt][64 lane][8 bf16]
__device__ __forceinline__ bf16x8 frag_piece(const bf16_t* hb, int group, int kt, int lane) {
    return *(const bf16x8*)(hb + (size_t)group * 8192 + kt * 512 + lane * 8);
}

// ---------------- output GEMM: h[128,512] x Wout^T + b_out -> out f32 [128][2048] ------------
__global__ __launch_bounds__(256) void k_out(
    const bf16_t* __restrict__ h,      // hbuf parity 0 (h_64), fragment image
    const float* __restrict__ Wout,    // [2048][512] f32 (inline cvt)
    const float* __restrict__ bout,
    float* __restrict__ out) {
    int lane = threadIdx.x & 63, w = threadIdx.x >> 6;
    int r0 = blockIdx.x * 32 + (w & 1) * 16;
    int g0 = blockIdx.y * 128 + (w >> 1) * 64;
    int group = r0 >> 4;
    f32x4 acc[4] = {};
    #pragma unroll 4
    for (int kt = 0; kt < 16; ++kt) {
        bf16x8 a = frag_piece(h, group, kt, lane);
        #pragma unroll
        for (int t = 0; t < 4; t++) {
            bf16x8 b = frag16f(Wout, g0 + 16 * t, HID, kt * 32, lane);
            acc[t] = MFMA16(a, b, acc[t], 0, 0, 0);
        }
    }
    #pragma unroll
    for (int t = 0; t < 4; t++) {
        int g = g0 + 16 * t + (lane & 15);
        float bs = bout[g];
        #pragma unroll
        for (int r = 0; r < 4; r++) {
            int row = r0 + ((lane >> 4) << 2) + r;
            out[(size_t)row * NFEAT + g] = acc[t][r] + bs;
        }
    }
}

extern "C" void kernel_launch(void* const* d_in, const int* in_sizes, int n_in,
                              void* d_out, int out_size, void* d_ws, size_t ws_size,
                              hipStream_t stream) {
    const int*   m       = (const int*)d_in[0];
    // d_in[1] = images (unused by reference)
    const float* emb_tab = (const float*)d_in[2];
    const float* W_ih    = (const float*)d_in[3];
    const float* W_hh    = (const float*)d_in[4];
    const float* b_ih    = (const float*)d_in[5];
    const float* b_hh    = (const float*)d_in[6];
    const float* W_out   = (const float*)d_in[7];
    const float* b_out   = (const float*)d_in[8];

    char* ws = (char*)d_ws;
    bf16_t*   xpb   = (bf16_t*)  (ws + 0);          // 8192*2048*2 = 33554432
    char*     hbuf  = (char*)    (ws + 33554432);   // 2 parity x 131072 = 262144
    unsigned* flags = (unsigned*)(ws + 33816576);   // 256 dwords

    k_xproj<<<dim3(64, 16), dim3(256), 0, stream>>>(m, emb_tab, W_ih, b_ih, b_hh, xpb, flags);

    k_rnn<<<dim3(64), dim3(256), 0, stream>>>(xpb, W_hh, hbuf, flags);

    // h_64 in parity 0
    k_out<<<dim3(4, 16), dim3(256), 0, stream>>>((const bf16_t*)hbuf, W_out, b_out,
                                                 (float*)d_out);
}